// Round 10
// baseline (143.974 us; speedup 1.0000x reference)
//
#include <hip/hip_runtime.h>
#include <math.h>

// Problem constants (B, NP, NQ, D) = (4, 256, 256, 512)
#define BB   4
#define NP   256
#define NQ   256
#define DD   512
#define DD4  (DD / 4)

typedef float f32x4 __attribute__((ext_vector_type(4)));

static constexpr float kScale = 1.0f / 22.627417f;  // 1/sqrt(512)

// ---------------------------------------------------------------------------
// Launch 1: gate table. 4 softmax rows per block of q_scores = qq.qk^T / T,
// written to gws[b][n][p] (1 MB of d_ws). Grid (64, 4).
// ---------------------------------------------------------------------------
__global__ __launch_bounds__(256) void gate_kernel(
    const float* __restrict__ qq,    // [B, NQ, D]
    const float* __restrict__ qk,    // [B, NP, D]
    float* __restrict__ gws)         // [B, NQ, NP]
{
    const int b  = blockIdx.y;
    const int n0 = blockIdx.x * 4;
    const int t  = threadIdx.x;

    const f32x4* krow = (const f32x4*)(qk + ((size_t)b * NP + t) * DD);
    const float* qb   = qq + ((size_t)b * NQ + n0) * DD;   // wave-uniform

    float acc[4] = {0.f, 0.f, 0.f, 0.f};
    #pragma unroll 8
    for (int d4 = 0; d4 < DD4; ++d4) {
        const f32x4 kv = krow[d4];
        #pragma unroll
        for (int r = 0; r < 4; ++r) {
            const float* qr = qb + r * DD + d4 * 4;
            acc[r] += qr[0] * kv.x + qr[1] * kv.y + qr[2] * kv.z + qr[3] * kv.w;
        }
    }

    __shared__ __align__(16) float ss[4][256];
    #pragma unroll
    for (int r = 0; r < 4; ++r) ss[r][t] = acc[r] * kScale;
    __syncthreads();

    const int r = t >> 6;
    const int g = t & 63;
    const f32x4 sv = ((const f32x4*)ss[r])[g];

    float m = fmaxf(fmaxf(sv.x, sv.y), fmaxf(sv.z, sv.w));
    #pragma unroll
    for (int off = 32; off >= 1; off >>= 1) m = fmaxf(m, __shfl_xor(m, off, 64));

    f32x4 ev;
    ev.x = expf(sv.x - m); ev.y = expf(sv.y - m);
    ev.z = expf(sv.z - m); ev.w = expf(sv.w - m);
    float s = (ev.x + ev.y) + (ev.z + ev.w);
    #pragma unroll
    for (int off = 32; off >= 1; off >>= 1) s += __shfl_xor(s, off, 64);

    ((f32x4*)(gws + ((size_t)b * NQ + n0 + r) * NP))[g] = ev * (1.0f / s);
}

// ---------------------------------------------------------------------------
// Launch 2, grid.x = 256 + 2048:
//  blocks [0,256):    type B: attn/log_attn = softmax(q.k^T/T), 4 rows each
//                     (placed first so they never tail the store pipeline).
//  blocks [256,2304): type A: store block owns tile (b, n0+0..7, p0+0..15).
//    ALL global reads hoisted before the burst: v rows + qv rows in
//    REGISTERS (8+8 f32x4), 128 gates in LDS. Then 64 PLAIN f32x4 stores
//    per thread with zero interleaved global loads — clean A/B of the
//    plain write-back drain rate (fill kernel: 6.7 TB/s) vs NT (~4.3).
// ---------------------------------------------------------------------------
__global__ __launch_bounds__(256) void store_kernel(
    const float* __restrict__ q,     // [B, NP, D]
    const float* __restrict__ k,     // [B, NP, D]
    const f32x4* __restrict__ v4,    // [B, NP, DD4]
    const f32x4* __restrict__ qv4,   // [B, NQ, DD4]
    const float* __restrict__ gws,   // [B, NQ, NP]
    f32x4* __restrict__ out4,        // [B, NQ, NP, DD4]
    float* __restrict__ attn_out,    // [B, NP, NP]
    float* __restrict__ logattn_out) // [B, NP, NP]
{
    const int t = threadIdx.x;

    if (blockIdx.x >= 256u) {
        // ---------------- type A: register-staged pure write burst --------
        const int idx = blockIdx.x - 256;      // 0..2047
        const int b   = idx >> 9;
        const int r   = idx & 511;
        const int n0  = (r >> 4) << 3;         // 0,8,...,248
        const int p0  = (r & 15) << 4;         // 0,16,...,240
        const int d4  = t & (DD4 - 1);
        const int h   = t >> 7;                // wave-uniform (0 or 1)

        // Stage this tile's 8x16 gates in LDS.
        __shared__ float gl[8][16];
        if (t < 128)
            gl[t >> 4][t & 15] =
                gws[((size_t)b * NQ + n0 + (t >> 4)) * NP + p0 + (t & 15)];
        __syncthreads();

        // Hoist all global reads: 8 v rows (this thread's p's) + 8 qv rows.
        const f32x4* vb  = v4  + (((size_t)b * NP + p0) << 7) + d4;
        const f32x4* qvb = qv4 + (((size_t)b * NQ + n0) << 7) + d4;
        f32x4 vv[8], qvv[8];
        #pragma unroll
        for (int i = 0; i < 8; ++i) vv[i]  = vb[(size_t)(2 * i + h) << 7];
        #pragma unroll
        for (int j = 0; j < 8; ++j) qvv[j] = qvb[(size_t)j << 7];

        // Pure plain-store burst: 64 x 16B per thread, 1KB/wave-inst.
        f32x4* ob = out4 + ((((size_t)b * NQ + n0) * NP + p0) << 7) + d4;
        #pragma unroll
        for (int j = 0; j < 8; ++j) {
            f32x4* obn = ob + (((size_t)j * NP) << 7);
            #pragma unroll
            for (int i = 0; i < 8; ++i) {
                const int pc = 2 * i + h;      // wave-uniform gate col
                obn[(size_t)pc << 7] = (vv[i] + qvv[j]) * gl[j][pc];
            }
        }
    } else {
        // ---------------- type B: attn / log_attn softmax ----------------
        const int idx = blockIdx.x;            // 0..255
        const int b   = idx >> 6;
        const int p0  = (idx & 63) * 4;

        const f32x4* krow = (const f32x4*)(k + ((size_t)b * NP + t) * DD);
        const float* qb   = q + ((size_t)b * NP + p0) * DD;   // wave-uniform

        float acc[4] = {0.f, 0.f, 0.f, 0.f};
        #pragma unroll 8
        for (int d4 = 0; d4 < DD4; ++d4) {
            const f32x4 kv = krow[d4];
            #pragma unroll
            for (int r = 0; r < 4; ++r) {
                const float* qr = qb + r * DD + d4 * 4;
                acc[r] += qr[0] * kv.x + qr[1] * kv.y + qr[2] * kv.z + qr[3] * kv.w;
            }
        }

        __shared__ __align__(16) float ss[4][256];
        #pragma unroll
        for (int r = 0; r < 4; ++r) ss[r][t] = acc[r] * kScale;
        __syncthreads();

        const int r = t >> 6;
        const int g = t & 63;
        const f32x4 sv = ((const f32x4*)ss[r])[g];

        float m = fmaxf(fmaxf(sv.x, sv.y), fmaxf(sv.z, sv.w));
        #pragma unroll
        for (int off = 32; off >= 1; off >>= 1)
            m = fmaxf(m, __shfl_xor(m, off, 64));

        f32x4 ev;
        ev.x = expf(sv.x - m); ev.y = expf(sv.y - m);
        ev.z = expf(sv.z - m); ev.w = expf(sv.w - m);
        float s = (ev.x + ev.y) + (ev.z + ev.w);
        #pragma unroll
        for (int off = 32; off >= 1; off >>= 1) s += __shfl_xor(s, off, 64);

        const float inv = 1.0f / s;
        const float lse = logf(s);

        const size_t base = ((size_t)b * NP + (p0 + r)) * 256;
        ((f32x4*)(attn_out + base))[g] = ev * inv;
        f32x4 lg;
        lg.x = (sv.x - m) - lse; lg.y = (sv.y - m) - lse;
        lg.z = (sv.z - m) - lse; lg.w = (sv.w - m) - lse;
        ((f32x4*)(logattn_out + base))[g] = lg;
    }
}

extern "C" void kernel_launch(void* const* d_in, const int* in_sizes, int n_in,
                              void* d_out, int out_size, void* d_ws, size_t ws_size,
                              hipStream_t stream) {
    // setup_inputs order: q, k, v, query(unused), query_q, query_k, query_v
    const float* q  = (const float*)d_in[0];
    const float* k  = (const float*)d_in[1];
    const float* v  = (const float*)d_in[2];
    const float* qq = (const float*)d_in[4];
    const float* qk = (const float*)d_in[5];
    const float* qv = (const float*)d_in[6];

    float* out = (float*)d_out;
    const size_t out_elems = (size_t)BB * NQ * NP * DD;          // 134,217,728
    float* attn_out    = out + out_elems;                         // [B,NP,256]
    float* logattn_out = attn_out + (size_t)BB * NP * 256;        // [B,NP,256]

    float* gws = (float*)d_ws;       // 4*256*256*4 = 1 MB of scratch

    // 1) gate table -> workspace.
    gate_kernel<<<dim3(NQ / 4, BB), 256, 0, stream>>>(qq, qk, gws);

    // 2) register-staged pure-write burst + (concurrent) attn/log_attn.
    store_kernel<<<256 + 2048, 256, 0, stream>>>(
        q, k, (const f32x4*)v, (const f32x4*)qv, gws,
        (f32x4*)out, attn_out, logattn_out);
}

// Round 11
// 133.718 us; speedup vs baseline: 1.0767x; 1.0767x over previous
//
#include <hip/hip_runtime.h>
#include <math.h>

// Problem constants (B, NP, NQ, D) = (4, 256, 256, 512)
#define BB   4
#define NP   256
#define NQ   256
#define DD   512
#define DD4  (DD / 4)

typedef float f32x4 __attribute__((ext_vector_type(4)));

static constexpr float kScale = 1.0f / 22.627417f;  // 1/sqrt(512)

// ---------------------------------------------------------------------------
// Launch 1: gate table. 4 softmax rows per block of q_scores = qq.qk^T / T,
// written to gws[b][n][p] (1 MB of d_ws). Grid (64, 4).
// ---------------------------------------------------------------------------
__global__ __launch_bounds__(256) void gate_kernel(
    const float* __restrict__ qq,    // [B, NQ, D]
    const float* __restrict__ qk,    // [B, NP, D]
    float* __restrict__ gws)         // [B, NQ, NP]
{
    const int b  = blockIdx.y;
    const int n0 = blockIdx.x * 4;
    const int t  = threadIdx.x;

    const f32x4* krow = (const f32x4*)(qk + ((size_t)b * NP + t) * DD);
    const float* qb   = qq + ((size_t)b * NQ + n0) * DD;   // wave-uniform

    float acc[4] = {0.f, 0.f, 0.f, 0.f};
    #pragma unroll 8
    for (int d4 = 0; d4 < DD4; ++d4) {
        const f32x4 kv = krow[d4];
        #pragma unroll
        for (int r = 0; r < 4; ++r) {
            const float* qr = qb + r * DD + d4 * 4;
            acc[r] += qr[0] * kv.x + qr[1] * kv.y + qr[2] * kv.z + qr[3] * kv.w;
        }
    }

    __shared__ __align__(16) float ss[4][256];
    #pragma unroll
    for (int r = 0; r < 4; ++r) ss[r][t] = acc[r] * kScale;
    __syncthreads();

    const int r = t >> 6;
    const int g = t & 63;
    const f32x4 sv = ((const f32x4*)ss[r])[g];

    float m = fmaxf(fmaxf(sv.x, sv.y), fmaxf(sv.z, sv.w));
    #pragma unroll
    for (int off = 32; off >= 1; off >>= 1) m = fmaxf(m, __shfl_xor(m, off, 64));

    f32x4 ev;
    ev.x = expf(sv.x - m); ev.y = expf(sv.y - m);
    ev.z = expf(sv.z - m); ev.w = expf(sv.w - m);
    float s = (ev.x + ev.y) + (ev.z + ev.w);
    #pragma unroll
    for (int off = 32; off >= 1; off >>= 1) s += __shfl_xor(s, off, 64);

    ((f32x4*)(gws + ((size_t)b * NQ + n0 + r) * NP))[g] = ev * (1.0f / s);
}

// ---------------------------------------------------------------------------
// Launch 2, grid.x = 256 + 2048:
//  blocks [0,256):    type B: attn/log_attn = softmax(q.k^T/T), 4 rows each.
//  blocks [256,2304): type A: store block owns tile (b, n0+0..7, p0+0..15).
//    ALL global reads hoisted before the burst: v rows + qv rows in
//    REGISTERS (8+8 f32x4), 128 gates in LDS. Then 64 NT f32x4 stores per
//    thread with zero interleaved global loads — the {NT, no-reads} cell of
//    the A/B matrix (R4={NT,reads}=132us, R10={plain,no-reads}=144us).
// ---------------------------------------------------------------------------
__global__ __launch_bounds__(256) void store_kernel(
    const float* __restrict__ q,     // [B, NP, D]
    const float* __restrict__ k,     // [B, NP, D]
    const f32x4* __restrict__ v4,    // [B, NP, DD4]
    const f32x4* __restrict__ qv4,   // [B, NQ, DD4]
    const float* __restrict__ gws,   // [B, NQ, NP]
    f32x4* __restrict__ out4,        // [B, NQ, NP, DD4]
    float* __restrict__ attn_out,    // [B, NP, NP]
    float* __restrict__ logattn_out) // [B, NP, NP]
{
    const int t = threadIdx.x;

    if (blockIdx.x >= 256u) {
        // ---------------- type A: register-staged pure NT write burst -----
        const int idx = blockIdx.x - 256;      // 0..2047
        const int b   = idx >> 9;
        const int r   = idx & 511;
        const int n0  = (r >> 4) << 3;         // 0,8,...,248
        const int p0  = (r & 15) << 4;         // 0,16,...,240
        const int d4  = t & (DD4 - 1);
        const int h   = t >> 7;                // wave-uniform (0 or 1)

        // Stage this tile's 8x16 gates in LDS.
        __shared__ float gl[8][16];
        if (t < 128)
            gl[t >> 4][t & 15] =
                gws[((size_t)b * NQ + n0 + (t >> 4)) * NP + p0 + (t & 15)];
        __syncthreads();

        // Hoist all global reads: 8 v rows (this thread's p's) + 8 qv rows.
        const f32x4* vb  = v4  + (((size_t)b * NP + p0) << 7) + d4;
        const f32x4* qvb = qv4 + (((size_t)b * NQ + n0) << 7) + d4;
        f32x4 vv[8], qvv[8];
        #pragma unroll
        for (int i = 0; i < 8; ++i) vv[i]  = vb[(size_t)(2 * i + h) << 7];
        #pragma unroll
        for (int j = 0; j < 8; ++j) qvv[j] = qvb[(size_t)j << 7];

        // Pure NT-store burst: 64 x 16B per thread, 1KB/wave-inst.
        f32x4* ob = out4 + ((((size_t)b * NQ + n0) * NP + p0) << 7) + d4;
        #pragma unroll
        for (int j = 0; j < 8; ++j) {
            f32x4* obn = ob + (((size_t)j * NP) << 7);
            #pragma unroll
            for (int i = 0; i < 8; ++i) {
                const int pc = 2 * i + h;      // wave-uniform gate col
                __builtin_nontemporal_store((vv[i] + qvv[j]) * gl[j][pc],
                                            obn + ((size_t)pc << 7));
            }
        }
    } else {
        // ---------------- type B: attn / log_attn softmax ----------------
        const int idx = blockIdx.x;            // 0..255
        const int b   = idx >> 6;
        const int p0  = (idx & 63) * 4;

        const f32x4* krow = (const f32x4*)(k + ((size_t)b * NP + t) * DD);
        const float* qb   = q + ((size_t)b * NP + p0) * DD;   // wave-uniform

        float acc[4] = {0.f, 0.f, 0.f, 0.f};
        #pragma unroll 8
        for (int d4 = 0; d4 < DD4; ++d4) {
            const f32x4 kv = krow[d4];
            #pragma unroll
            for (int r = 0; r < 4; ++r) {
                const float* qr = qb + r * DD + d4 * 4;
                acc[r] += qr[0] * kv.x + qr[1] * kv.y + qr[2] * kv.z + qr[3] * kv.w;
            }
        }

        __shared__ __align__(16) float ss[4][256];
        #pragma unroll
        for (int r = 0; r < 4; ++r) ss[r][t] = acc[r] * kScale;
        __syncthreads();

        const int r = t >> 6;
        const int g = t & 63;
        const f32x4 sv = ((const f32x4*)ss[r])[g];

        float m = fmaxf(fmaxf(sv.x, sv.y), fmaxf(sv.z, sv.w));
        #pragma unroll
        for (int off = 32; off >= 1; off >>= 1)
            m = fmaxf(m, __shfl_xor(m, off, 64));

        f32x4 ev;
        ev.x = expf(sv.x - m); ev.y = expf(sv.y - m);
        ev.z = expf(sv.z - m); ev.w = expf(sv.w - m);
        float s = (ev.x + ev.y) + (ev.z + ev.w);
        #pragma unroll
        for (int off = 32; off >= 1; off >>= 1) s += __shfl_xor(s, off, 64);

        const float inv = 1.0f / s;
        const float lse = logf(s);

        const size_t base = ((size_t)b * NP + (p0 + r)) * 256;
        ((f32x4*)(attn_out + base))[g] = ev * inv;
        f32x4 lg;
        lg.x = (sv.x - m) - lse; lg.y = (sv.y - m) - lse;
        lg.z = (sv.z - m) - lse; lg.w = (sv.w - m) - lse;
        ((f32x4*)(logattn_out + base))[g] = lg;
    }
}

extern "C" void kernel_launch(void* const* d_in, const int* in_sizes, int n_in,
                              void* d_out, int out_size, void* d_ws, size_t ws_size,
                              hipStream_t stream) {
    // setup_inputs order: q, k, v, query(unused), query_q, query_k, query_v
    const float* q  = (const float*)d_in[0];
    const float* k  = (const float*)d_in[1];
    const float* v  = (const float*)d_in[2];
    const float* qq = (const float*)d_in[4];
    const float* qk = (const float*)d_in[5];
    const float* qv = (const float*)d_in[6];

    float* out = (float*)d_out;
    const size_t out_elems = (size_t)BB * NQ * NP * DD;          // 134,217,728
    float* attn_out    = out + out_elems;                         // [B,NP,256]
    float* logattn_out = attn_out + (size_t)BB * NP * 256;        // [B,NP,256]

    float* gws = (float*)d_ws;       // 4*256*256*4 = 1 MB of scratch

    // 1) gate table -> workspace.
    gate_kernel<<<dim3(NQ / 4, BB), 256, 0, stream>>>(qq, qk, gws);

    // 2) register-staged pure-NT-write burst + (concurrent) attn/log_attn.
    store_kernel<<<256 + 2048, 256, 0, stream>>>(
        q, k, (const f32x4*)v, (const f32x4*)qv, gws,
        (f32x4*)out, attn_out, logattn_out);
}